// Round 20
// baseline (457.020 us; speedup 1.0000x reference)
//
#include <hip/hip_runtime.h>
#include <math.h>

typedef _Float16 f16;
typedef unsigned int u32;
typedef __attribute__((ext_vector_type(8))) f16 f16x8;
typedef __attribute__((ext_vector_type(4))) f16 f16x4;
typedef __attribute__((ext_vector_type(4))) float f32x4;
typedef __attribute__((ext_vector_type(16))) float f32x16;

#define DEV static __device__ __forceinline__

#define SEQ 2048
#define DMODEL 1536
#define NHEADS 8
#define DQK 128
#define DVV 192
#define QKVW 1344
#define SCALEQK 0.08838834764831845f
#define LOG2E 1.4426950408889634f

// ---------------- workspace layout (bytes) ----------------
#define OFF_WQKVT 0ull
#define OFF_WOUTT 4128768ull
#define OFF_XH    8847360ull
#define OFF_Q     21430272ull
#define OFF_K     29818880ull
#define OFF_V     30867456ull
#define OFF_VT    32440320ull
#define OFF_PART  34013184ull
#define OFF_SG    35061760ull
#define OFF_BIASC 35062784ull
#define OFF_AO    43451392ull
#define OFF_OP    56034304ull          // f16 [256][2][128][192] = 25,165,824
#define OFF_LS    81200128ull          // f32 [256][2][128] = 262,144
#define OFF_CNT   81462272ull          // u32 [256]

DEV float fexp2(float x){
#if __has_builtin(__builtin_amdgcn_exp2f)
  return __builtin_amdgcn_exp2f(x);
#else
  return exp2f(x);
#endif
}
DEV float frcp(float x){
#if __has_builtin(__builtin_amdgcn_rcpf)
  return __builtin_amdgcn_rcpf(x);
#else
  return 1.0f/x;
#endif
}

typedef u32 __attribute__((address_space(1))) u32g;
typedef u32 __attribute__((address_space(3))) u32l;
DEV void g2l16(const void* g, void* l){
  __builtin_amdgcn_global_load_lds((const u32g*)g, (u32l*)l, 16, 0, 0);
}

#define MFMA32(a,b,c) __builtin_amdgcn_mfma_f32_32x32x16_f16(a,b,c,0,0,0)
#define MFMA16(a,b,c) __builtin_amdgcn_mfma_f32_16x16x32_f16(a,b,c,0,0,0)

DEV f32x16 zero16(){
  f32x16 v;
  #pragma unroll
  for (int i=0;i<16;i++) v[i]=0.f;
  return v;
}
DEV f32x4 zero4(){
  f32x4 v;
  #pragma unroll
  for (int i=0;i<4;i++) v[i]=0.f;
  return v;
}

// fast exact-GELU: erf via Abramowitz-Stegun 7.1.26 (|err| <= 1.5e-7)
DEV float gelu_f(float x){
  float z  = 0.70710678118654752440f * x;
  float az = fabsf(z);
  float t  = frcp(1.f + 0.3275911f*az);
  float poly = t*(0.254829592f + t*(-0.284496736f + t*(1.421413741f +
               t*(-1.453152027f + t*1.061405429f))));
  float e  = 1.f - poly*fexp2(-z*z*LOG2E);
  float er = (z < 0.f) ? -e : e;
  return 0.5f*x*(1.f + er);
}

DEV void pvar_body(const float* __restrict__ pw, float* __restrict__ partials,
                   char* smem, int id, int tid){
  int q = tid & 31, rg = tid >> 5;
  f32x4 s1 = zero4(), s2 = zero4();
  const float* p0 = pw + ((size_t)id*512 + rg)*128 + q*4;
  #pragma unroll 4
  for (int it=0; it<64; it++){
    f32x4 v = *(const f32x4*)(p0 + (size_t)it*1024);
    s1 += v; s2 += v*v;
  }
  f32x4* r1 = (f32x4*)smem; f32x4* r2 = r1 + 256;
  r1[tid] = s1; r2[tid] = s2;
  __syncthreads();
  if (tid < 64){
    int qq = tid & 31;
    f32x4* rr = (tid >= 32) ? r2 : r1;
    f32x4 a = rr[qq];
    #pragma unroll
    for (int g=1; g<8; g++) a += rr[g*32+qq];
    *(f32x4*)(partials + (size_t)id*256 + ((tid>=32)?128:0) + qq*4) = a;
  }
}

// ======= K1: pvar (bids 0-1023, serpentine) || wtrans || X cast =======
__global__ __launch_bounds__(256) void k1_prep(const float* __restrict__ wq, f16* __restrict__ wqT,
                                               const float* __restrict__ wo, f16* __restrict__ woT,
                                               const float* __restrict__ X, f16* __restrict__ Xh,
                                               const float* __restrict__ pw, float* __restrict__ partials){
  __shared__ char sm[8192];
  int bid = blockIdx.x, tid = threadIdx.x;
  if (bid < 1024){
    pvar_body(pw, partials, sm, 1023 - bid, tid);
    return;
  }
  if (bid >= 5344){
    size_t i0 = (size_t)(bid - 5344)*2048 + (size_t)tid*8;
    f32x4 a = *(const f32x4*)(X + i0);
    f32x4 b = *(const f32x4*)(X + i0 + 4);
    f16x8 o;
    #pragma unroll
    for (int e=0;e<4;e++){ o[e] = (f16)a[e]; o[4+e] = (f16)b[e]; }
    *(f16x8*)(Xh + i0) = o;
    return;
  }
  float (*t)[33] = (float(*)[33])sm;
  int wb_ = bid - 1024;
  int tx = tid & 31, ty = tid >> 5;
  const float* src; f16* dst; int N, x, y;
  if (wb_ < 2016){ src = wq; dst = wqT; N = 1344; x = wb_ % 48; y = wb_ / 48; }
  else { int b2 = wb_ - 2016; src = wo; dst = woT; N = 1536; x = b2 % 48; y = b2 / 48; }
  int k0 = x*32, n0 = y*32;
  #pragma unroll
  for (int i=0;i<4;i++){ int r = ty+8*i; t[r][tx] = src[(size_t)(k0+r)*N + n0+tx]; }
  __syncthreads();
  #pragma unroll
  for (int i=0;i<4;i++){ int r = ty+8*i; dst[(size_t)(n0+r)*1536 + k0+tx] = (f16)t[tx][r]; }
}

// ================= finvar (+ zero attn counters) =================
__global__ __launch_bounds__(256) void finvar_k(const float* __restrict__ partials,
    const float* __restrict__ rvar, const float* __restrict__ gamma,
    const float* __restrict__ beta, float* __restrict__ sg, float* __restrict__ sb,
    u32* __restrict__ cnt){
  __shared__ float sh[256];
  int tid = threadIdx.x;
  cnt[tid] = 0u;                      // re-zeroed every call, before attn
  int c = tid & 127, wh = tid >> 7;
  float acc = 0.f;
  #pragma unroll 8
  for (int i=0;i<1024;i++) acc += partials[i*256 + wh*128 + c];
  sh[tid] = acc;
  __syncthreads();
  if (tid < 128){
    float s1 = sh[tid], s2 = sh[tid+128];
    const float Minv = 1.f/524288.f;
    float m = s1*Minv;
    float var = s2*Minv - m*m;
    float rv = rvar[tid]*0.9f + 0.1f*var;
    sg[tid] = rsqrtf(rv + 1e-5f)*gamma[tid];
    sb[tid] = beta[tid];
  }
}

// ======== fused qkv-GEMM + LayerNorm: BM=128, BN=NF*32, double-buffered, setprio(T5) ========
template<int NF>
DEV void qkvln_body(const f16* __restrict__ A, const f16* __restrict__ WT, int nbase,
                    const float* __restrict__ lnw, const float* __restrict__ lnb,
                    f16* __restrict__ d0, size_t bstride,
                    char* lds, int mt, int tid){
  const int BN = NF*32;
  int mb = mt*128;
  int w = tid>>6, lane = tid&63, li = lane&31, h = lane>>5;
  int srow = lane>>3, sc = lane&7;
  f32x16 acc[NF];
  #pragma unroll
  for (int nf=0;nf<NF;nf++) acc[nf] = zero16();

#define QL_STAGE(buf, kt_) do { \
    char* ad = lds + (buf)*40960; \
    _Pragma("unroll") \
    for (int s=0;s<4;s++){ \
      int slot = w*4+s; int row = slot*8 + srow; int cs = sc ^ (srow&7); \
      g2l16(A + (size_t)(mb+row)*DMODEL + (kt_)*64 + cs*8, ad + slot*1024); \
    } \
    char* bd = lds + (buf)*40960 + 16384; \
    _Pragma("unroll") \
    for (int s=0;s<NF;s++){ \
      int slot = w*NF+s; int row = slot*8 + srow; int cs = sc ^ (srow&7); \
      g2l16(WT + (size_t)(nbase+row)*DMODEL + (kt_)*64 + cs*8, bd + slot*1024); \
    } } while(0)

  QL_STAGE(0,0);
  __syncthreads();
  for (int kt=0; kt<24; kt++){
    int cur = kt&1;
    if (kt<23) QL_STAGE(cur^1, kt+1);
    const char* ad = lds + cur*40960;
    const char* bd = lds + cur*40960 + 16384;
    __builtin_amdgcn_s_setprio(1);
    #pragma unroll
    for (int ks=0; ks<4; ks++){
      int cso = ((2*ks+h) ^ (li&7))*16;
      f16x8 af = *(const f16x8*)(ad + (w*32 + li)*128 + cso);
      #pragma unroll
      for (int nf=0; nf<NF; nf++){
        f16x8 bf = *(const f16x8*)(bd + (nf*32 + li)*128 + cso);
        acc[nf] = MFMA32(af, bf, acc[nf]);
      }
    }
    __builtin_amdgcn_s_setprio(0);
    __syncthreads();
  }

  float Wc[NF], Bc[NF];
  #pragma unroll
  for (int nf=0;nf<NF;nf++){ Wc[nf] = lnw[nf*32+li]; Bc[nf] = lnb[nf*32+li]; }
  const float invBN = 1.f/(float)BN;
  #pragma unroll
  for (int rr=0; rr<16; rr++){
    float s = 0.f;
    #pragma unroll
    for (int nf=0;nf<NF;nf++) s += acc[nf][rr];
    #pragma unroll
    for (int d=16; d>=1; d>>=1) s += __shfl_xor(s, d);
    float mu = s*invBN;
    float vv = 0.f;
    #pragma unroll
    for (int nf=0;nf<NF;nf++){ float dd = acc[nf][rr]-mu; vv += dd*dd; }
    #pragma unroll
    for (int d=16; d>=1; d>>=1) vv += __shfl_xor(vv, d);
    float istd = rsqrtf(vv*invBN + 1e-5f);
    int r = (rr&3) + 8*(rr>>2) + 4*h;
    int m = mb + w*32 + r;
    int bb = m >> 11, nseq = m & 2047;
    f16* drow = d0 + (size_t)bb*bstride + (size_t)nseq*BN;
    #pragma unroll
    for (int nf=0;nf<NF;nf++)
      drow[nf*32+li] = (f16)((acc[nf][rr]-mu)*istd*Wc[nf] + Bc[nf]);
  }
#undef QL_STAGE
}

// bias_gemm body: f32 pairwise read, no LDS
DEV void bias_body(const float* __restrict__ pw,
    const float* __restrict__ sg, const float* __restrict__ sb,
    const float* __restrict__ wb, f16* __restrict__ biasc, int bias_id, int tid){
  int w = tid>>6, lane = tid&63;
  int il = lane&15, kg = lane>>4;
  f16x8 bw[4];
  float sgr[32], sbr[32];
  #pragma unroll
  for (int t=0;t<4;t++)
    #pragma unroll
    for (int e=0;e<8;e++){
      int k = t*32 + kg*8 + e;
      bw[t][e] = (f16)((il<8) ? wb[k*8 + il] : 0.f);
      sgr[t*8+e] = sg[k];
      sbr[t*8+e] = sb[k];
    }
  for (int it=0; it<8; it++){
    int tile = bias_id*4 + w + it*4096;
    size_t rg = (size_t)tile*16 + il;
    f32x4 acc = zero4();
    #pragma unroll
    for (int t=0;t<4;t++){
      const float* sp = pw + rg*128 + t*32 + kg*8;
      f32x4 v0 = *(const f32x4*)sp;
      f32x4 v1 = *(const f32x4*)(sp+4);
      f16x8 af;
      #pragma unroll
      for (int e=0;e<4;e++) af[e]   = (f16)gelu_f(v0[e]*sgr[t*8+e]   + sbr[t*8+e]);
      #pragma unroll
      for (int e=0;e<4;e++) af[4+e] = (f16)gelu_f(v1[e]*sgr[t*8+4+e] + sbr[t*8+4+e]);
      acc = MFMA16(af, bw[t], acc);
    }
    if (il < 8){
      #pragma unroll
      for (int r=0;r<4;r++){
        size_t rr = (size_t)tile*16 + kg*4 + r;
        int bb = (int)(rr >> 18);
        int rem = (int)(rr & 262143);
        int ii = rem >> 9, jj = rem & 511;
        biasc[(((size_t)(bb*8 + il)*512) + ii)*512 + jj] = (f16)acc[r];
      }
    }
  }
}

// ========== K2': qkvln GEMM (bids 0-319, front, XCD-chunked) || bias_gemm (320-1343) ==========
__global__ __launch_bounds__(256,2) void k2_qkvln_bias(const f16* __restrict__ Xh,
    const f16* __restrict__ WT,
    const float* __restrict__ qw, const float* __restrict__ qb,
    const float* __restrict__ kw, const float* __restrict__ kb,
    const float* __restrict__ vw, const float* __restrict__ vb,
    f16* __restrict__ Q, f16* __restrict__ K, f16* __restrict__ V,
    const float* __restrict__ pw, const float* __restrict__ sg, const float* __restrict__ sb,
    const float* __restrict__ wb, f16* __restrict__ biasc){
  __shared__ char smem[81920];
  int bid = blockIdx.x, tid = threadIdx.x;
  if (bid < 320){
    int l = (bid&7)*40 + (bid>>3);           // XCD-chunked (320 = 8*40), seg-major
    int seg = l >> 5, mt = l & 31;
    if (seg < 8)
      qkvln_body<4>(Xh, WT, seg*128, qw, qb, Q + (size_t)seg*SEQ*DQK,
                    (size_t)NHEADS*SEQ*DQK, smem, mt, tid);
    else if (seg == 8)
      qkvln_body<4>(Xh, WT, 1024, kw, kb, K, (size_t)SEQ*DQK, smem, mt, tid);
    else
      qkvln_body<6>(Xh, WT, 1152, vw, vb, V, (size_t)SEQ*DVV, smem, mt, tid);
  } else {
    bias_body(pw, sg, sb, wb, biasc, bid - 320, tid);
  }
}

// ================= K4: vtrans only (768 blocks, small LDS, high occupancy) =================
__global__ __launch_bounds__(256) void k4_vtrans(const f16* __restrict__ V, f16* __restrict__ VT){
  __shared__ f16 t[32][33];
  int id = blockIdx.x, tid = threadIdx.x;
  int b = id / 384, rem = id - b*384;
  int d0 = (rem % 6)*32, j0 = (rem / 6)*32;
  int tx = tid & 31, ty = tid >> 5;
  #pragma unroll
  for (int i=0;i<4;i++){ int r = ty+8*i; t[r][tx] = V[((size_t)b*SEQ + j0+r)*DVV + d0+tx]; }
  __syncthreads();
  #pragma unroll
  for (int i=0;i<4;i++){ int r = ty+8*i; VT[((size_t)b*DVV + d0+r)*SEQ + j0+tx] = t[tx][r]; }
}

// ===== K5: fused attention, j-split (grid 512, 2 blocks/CU), fused atomic-tail combine =====
__global__ __launch_bounds__(256,2) void attn(const f16* __restrict__ Q, const f16* __restrict__ K,
                                              const f16* __restrict__ VT, const f16* __restrict__ biasc,
                                              f16* __restrict__ Opart, float* __restrict__ Ls,
                                              f16* __restrict__ AO, u32* __restrict__ cnt){
  __shared__ char lds[81920];
  __shared__ u32 ordsh;
  int bid = blockIdx.x;
  int half = bid & 1, bgqt = bid >> 1;
  int bg = bgqt & 15, qt = bgqt >> 4;
  int b = bg >> 3;
  int tid = threadIdx.x;
  int w = tid >> 6, lane = tid & 63;
  int li = lane & 31, h = lane >> 5;

  const f16* Qb = Q  + (size_t)bg*SEQ*DQK;
  const f16* Kb = K  + (size_t)b*SEQ*DQK;
  const f16* Vb = VT + (size_t)b*DVV*SEQ;

  int qrow = qt*128 + w*32 + li;
  f16x8 qf[8];
  #pragma unroll
  for (int ks=0; ks<8; ks++)
    qf[ks] = *(const f16x8*)(Qb + (size_t)qrow*DQK + ks*16 + h*8);

  const f16* brow = biasc + ((size_t)bg*512 + (qrow>>2))*512;

  f32x16 oacc[6];
  #pragma unroll
  for (int nf=0;nf<6;nf++) oacc[nf] = zero16();
  float lsum = 0.f;

  int kl_row = lane >> 4, kl_c = lane & 15;
  int vl_row = lane >> 3, vl_c = lane & 7;

#define STAGE(buf, jt_) do { \
    char* kd = lds + (buf)*40960; \
    const f16* ksrc = Kb + (size_t)(jt_)*64*DQK; \
    _Pragma("unroll") \
    for (int s=0;s<4;s++){ \
      int slot = w*4+s; int jr = slot*4 + kl_row; int cs = kl_c ^ (jr&7); \
      g2l16(ksrc + (size_t)jr*DQK + cs*8, kd + slot*1024); \
    } \
    char* vd = lds + (buf)*40960 + 16384; \
    _Pragma("unroll") \
    for (int s=0;s<6;s++){ \
      int slot = w*6+s; int dvr = slot*8 + vl_row; int cs = vl_c ^ (dvr&7); \
      g2l16(Vb + (size_t)dvr*SEQ + (size_t)(jt_)*64 + cs*8, vd + slot*1024); \
    } } while(0)

  int jt0 = half*16;
  STAGE(0, jt0);

  const float CS = SCALEQK * (2.f*LOG2E/5.f);
  const float CB = 2.f*LOG2E/5.f;
  const float CP = 5.f*LOG2E;

  for (int jj=0; jj<16; jj++){
    int jt = jt0 + jj;
    int cur = jj & 1;
    __syncthreads();
    if (jj < 15) STAGE(cur^1, jt+1);
    const char* kb_ = lds + cur*40960;
    const char* vb_ = lds + cur*40960 + 16384;

    f32x16 s0 = zero16(), s1 = zero16();
    __builtin_amdgcn_s_setprio(1);
    #pragma unroll
    for (int ks=0; ks<8; ks++){
      int cso = ((2*ks + h) ^ (li&7))*16;
      f16x8 kf0 = *(const f16x8*)(kb_ + (     li)*256 + cso);
      f16x8 kf1 = *(const f16x8*)(kb_ + (32 + li)*256 + cso);
      s0 = MFMA32(kf0, qf[ks], s0);
      s1 = MFMA32(kf1, qf[ks], s1);
    }
    __builtin_amdgcn_s_setprio(0);

    f16x8 pa[2][2];
    #pragma unroll
    for (int sub=0; sub<2; sub++){
      const f32x16& sacc = sub ? s1 : s0;
      int jb4 = jt*16 + sub*8;
      f16x8 bv = *(const f16x8*)(brow + jb4);
      float bt[4];
      #pragma unroll
      for (int q=0;q<4;q++){
        float b0 = (float)bv[2*q], b1 = (float)bv[2*q+1];
        bt[q] = (h ? b1 : b0) * CB;
      }
      float p[16], xp[16];
      #pragma unroll
      for (int r=0;r<16;r++){
        float u2 = sacc[r]*CS + bt[r>>2];
        float E  = fexp2(u2);
        float tn = 1.f - 2.f*frcp(E + 1.f);
        float pr = fexp2(tn * CP);
        p[r] = pr;
        lsum += pr;
      }
      #pragma unroll
      for (int r=0;r<16;r++) xp[r] = __shfl_xor(p[r], 32);
      #pragma unroll
      for (int ks2=0; ks2<2; ks2++){
        #pragma unroll
        for (int e=0;e<4;e++) pa[sub][ks2][e] = (f16)(h ? xp[8*ks2+4+e] : p[8*ks2+e]);
        #pragma unroll
        for (int e=4;e<8;e++) pa[sub][ks2][e] = (f16)(h ? p[8*ks2+e]    : xp[8*ks2+e-4]);
      }
    }
    __builtin_amdgcn_s_setprio(1);
    #pragma unroll
    for (int sub=0; sub<2; sub++)
      #pragma unroll
      for (int ks2=0; ks2<2; ks2++)
        #pragma unroll
        for (int nf=0; nf<6; nf++){
          int dvr = nf*32 + li;
          int cj = (sub*4 + 2*ks2 + h) ^ (dvr&7);
          f16x8 vf = *(const f16x8*)(vb_ + dvr*128 + cj*16);
          oacc[nf] = MFMA32(pa[sub][ks2], vf, oacc[nf]);
        }
    __builtin_amdgcn_s_setprio(0);
  }
  f16* Ob = Opart + (size_t)(bgqt*2 + half)*128*192;
  #pragma unroll
  for (int nf=0; nf<6; nf++)
    #pragma unroll
    for (int r=0;r<16;r++){
      int il = (r&3) + 8*(r>>2) + 4*h;
      Ob[(size_t)(w*32 + il)*192 + nf*32 + li] = (f16)oacc[nf][r];
    }
  float ltot = lsum + __shfl_xor(lsum, 32);
  if (h == 0) Ls[(size_t)(bgqt*2 + half)*128 + w*32 + li] = ltot;

  // ---- fused combine: second finisher for this bgqt normalizes & writes AO ----
  __threadfence();                               // release: flush Opart/Ls device-wide
  if (tid == 0) ordsh = atomicAdd(&cnt[bgqt], 1u);
  __syncthreads();
  if (ordsh == 1u){
    __threadfence();                             // acquire: see other block's writes
    int row = tid >> 1, cs0 = (tid & 1)*96;
    float l0 = Ls[(size_t)(bgqt*2 + 0)*128 + row];
    float l1 = Ls[(size_t)(bgqt*2 + 1)*128 + row];
    float linv = 1.f / (l0 + l1);
    const f16* P0 = Opart + ((size_t)(bgqt*2 + 0)*128 + row)*192 + cs0;
    const f16* P1 = Opart + ((size_t)(bgqt*2 + 1)*128 + row)*192 + cs0;
    int g = bg & 7;
    int n = qt*128 + row;
    f16* dst = AO + ((size_t)(b*SEQ + n)*NHEADS + g)*DVV + cs0;
    #pragma unroll
    for (int j=0;j<12;j++){
      f16x8 a = *(const f16x8*)(P0 + 8*j);
      f16x8 c = *(const f16x8*)(P1 + 8*j);
      f16x8 o;
      #pragma unroll
      for (int e=0;e<8;e++) o[e] = (f16)(((float)a[e] + (float)c[e]) * linv);
      *(f16x8*)(dst + 8*j) = o;
    }
  }
#undef STAGE
}

// ================= K6: out GEMM (256x64 tile, XCD-chunked) =================
DEV void gemm256_body(const f16* __restrict__ A, const f16* __restrict__ WT,
                      float* __restrict__ C, int ldc, const float* __restrict__ bo,
                      char* lds, int bx, int by, int tid){
  int nb = bx*64, mb = by*256;
  int w = tid>>6, lane = tid&63, li = lane&31, h = lane>>5;
  int srow = lane>>3, sc = lane&7;
  f32x16 acc[2][2];
  acc[0][0]=zero16(); acc[0][1]=zero16(); acc[1][0]=zero16(); acc[1][1]=zero16();

#define G_STAGE(buf, kt_) do { \
    char* ad = lds + (buf)*40960; \
    _Pragma("unroll") \
    for (int s=0;s<8;s++){ \
      int slot = w*8+s; int mlr = slot*8 + srow; int cs = sc ^ (srow&7); \
      g2l16(A + (size_t)(mb+mlr)*DMODEL + (kt_)*64 + cs*8, ad + slot*1024); \
    } \
    char* bd = lds + (buf)*40960 + 32768; \
    _Pragma("unroll") \
    for (int s=0;s<2;s++){ \
      int slot = w*2+s; int nl = slot*8 + srow; int cs = sc ^ (srow&7); \
      g2l16(WT + (size_t)(nb+nl)*DMODEL + (kt_)*64 + cs*8, bd + slot*1024); \
    } } while(0)

  G_STAGE(0,0);
  __syncthreads();
  for (int kt=0; kt<24; kt++){
    int cur = kt&1;
    if (kt<23) G_STAGE(cur^1, kt+1);
    const char* ad = lds + cur*40960;
    const char* bd = lds + cur*40960 + 32768;
    #pragma unroll
    for (int ks=0; ks<4; ks++){
      int cso = ((2*ks+h) ^ (li&7))*16;
      f16x8 a0 = *(const f16x8*)(ad + (w*64      + li)*128 + cso);
      f16x8 a1 = *(const f16x8*)(ad + (w*64 + 32 + li)*128 + cso);
      f16x8 b0 = *(const f16x8*)(bd + (           li)*128 + cso);
      f16x8 b1 = *(const f16x8*)(bd + (      32 + li)*128 + cso);
      acc[0][0] = MFMA32(a0, b0, acc[0][0]);
      acc[0][1] = MFMA32(a0, b1, acc[0][1]);
      acc[1][0] = MFMA32(a1, b0, acc[1][0]);
      acc[1][1] = MFMA32(a1, b1, acc[1][1]);
    }
    __syncthreads();
  }
  float bo0 = bo ? bo[nb+li] : 0.f, bo1 = bo ? bo[nb+32+li] : 0.f;
  #pragma unroll
  for (int mi=0; mi<2; mi++)
    #pragma unroll
    for (int nf=0; nf<2; nf++)
      #pragma unroll
      for (int r=0;r<16;r++){
        int m = mb + w*64 + mi*32 + (r&3) + 8*(r>>2) + 4*h;
        int n = nb + nf*32 + li;
        C[(size_t)m*ldc + n] = acc[mi][nf][r] + (nf ? bo1 : bo0);
      }
#undef G_STAGE
}

__global__ __launch_bounds__(256,2) void out_gemm(const f16* __restrict__ A, const f16* __restrict__ WT,
                                                  const float* __restrict__ bo, float* __restrict__ out){
  __shared__ char lds[81920];
  int bid = blockIdx.x, tid = threadIdx.x;
  int l = (bid&7)*48 + (bid>>3);
  gemm256_body(A, WT, out, DMODEL, bo, lds, l%24, l/24, tid);
}

extern "C" void kernel_launch(void* const* d_in, const int* in_sizes, int n_in,
                              void* d_out, int out_size, void* d_ws, size_t ws_size,
                              hipStream_t stream) {
  (void)in_sizes; (void)n_in; (void)out_size; (void)ws_size;
  const float* x        = (const float*)d_in[0];
  const float* pairwise = (const float*)d_in[1];
  const float* w_qkv    = (const float*)d_in[2];
  const float* q_w      = (const float*)d_in[3];
  const float* q_b      = (const float*)d_in[4];
  const float* k_w      = (const float*)d_in[5];
  const float* k_b      = (const float*)d_in[6];
  const float* v_w      = (const float*)d_in[7];
  const float* v_b      = (const float*)d_in[8];
  const float* bgamma   = (const float*)d_in[9];
  const float* bbeta    = (const float*)d_in[10];
  const float* brvar    = (const float*)d_in[11];
  const float* w_bias   = (const float*)d_in[12];
  const float* w_out    = (const float*)d_in[13];
  const float* b_out    = (const float*)d_in[14];
  float* out = (float*)d_out;

  char* ws = (char*)d_ws;
  f16*   wqkvT = (f16*)(ws + OFF_WQKVT);
  f16*   woutT = (f16*)(ws + OFF_WOUTT);
  f16*   Xh    = (f16*)(ws + OFF_XH);
  f16*   Qh    = (f16*)(ws + OFF_Q);
  f16*   Kh    = (f16*)(ws + OFF_K);
  f16*   Vh    = (f16*)(ws + OFF_V);
  f16*   VTh   = (f16*)(ws + OFF_VT);
  float* part  = (float*)(ws + OFF_PART);
  float* sg    = (float*)(ws + OFF_SG);
  float* sb    = sg + 128;
  f16*   biasc = (f16*)(ws + OFF_BIASC);
  f16*   AOh   = (f16*)(ws + OFF_AO);
  f16*   Opart = (f16*)(ws + OFF_OP);
  float* Lsw   = (float*)(ws + OFF_LS);
  u32*   cnt   = (u32*)(ws + OFF_CNT);

  k1_prep<<<8416, 256, 0, stream>>>(w_qkv, wqkvT, w_out, woutT, x, Xh, pairwise, part);
  finvar_k<<<1, 256, 0, stream>>>(part, brvar, bgamma, bbeta, sg, sb, cnt);
  k2_qkvln_bias<<<1344, 256, 0, stream>>>(Xh, wqkvT, q_w,q_b,k_w,k_b,v_w,v_b,
                                          Qh, Kh, Vh, pairwise, sg, sb, w_bias, biasc);
  k4_vtrans<<<768, 256, 0, stream>>>(Vh, VTh);
  attn<<<512, 256, 0, stream>>>(Qh, Kh, VTh, biasc, Opart, Lsw, AOh, cnt);
  out_gemm<<<384, 256, 0, stream>>>(AOh, woutT, b_out, out);
}

// Round 21
// 419.189 us; speedup vs baseline: 1.0902x; 1.0902x over previous
//
#include <hip/hip_runtime.h>
#include <math.h>

typedef _Float16 f16;
typedef unsigned int u32;
typedef __attribute__((ext_vector_type(8))) f16 f16x8;
typedef __attribute__((ext_vector_type(4))) f16 f16x4;
typedef __attribute__((ext_vector_type(4))) float f32x4;
typedef __attribute__((ext_vector_type(16))) float f32x16;

#define DEV static __device__ __forceinline__

#define SEQ 2048
#define DMODEL 1536
#define NHEADS 8
#define DQK 128
#define DVV 192
#define QKVW 1344
#define SCALEQK 0.08838834764831845f
#define LOG2E 1.4426950408889634f

// ---------------- workspace layout (bytes) ----------------
#define OFF_WQKVT 0ull
#define OFF_WOUTT 4128768ull
#define OFF_XH    8847360ull
#define OFF_Q     21430272ull
#define OFF_K     29818880ull
#define OFF_V     30867456ull
#define OFF_VT    32440320ull
#define OFF_PART  34013184ull
#define OFF_SG    35061760ull
#define OFF_BIASC 35062784ull
#define OFF_AO    43451392ull
#define OFF_OP    56034304ull          // f16 [256][2][128][192] = 25,165,824
#define OFF_LS    81200128ull          // f32 [256][2][128] = 262,144
#define OFF_CNT   81462272ull          // u32 [256]

DEV float fexp2(float x){
#if __has_builtin(__builtin_amdgcn_exp2f)
  return __builtin_amdgcn_exp2f(x);
#else
  return exp2f(x);
#endif
}
DEV float frcp(float x){
#if __has_builtin(__builtin_amdgcn_rcpf)
  return __builtin_amdgcn_rcpf(x);
#else
  return 1.0f/x;
#endif
}

typedef u32 __attribute__((address_space(1))) u32g;
typedef u32 __attribute__((address_space(3))) u32l;
DEV void g2l16(const void* g, void* l){
  __builtin_amdgcn_global_load_lds((const u32g*)g, (u32l*)l, 16, 0, 0);
}

#define MFMA32(a,b,c) __builtin_amdgcn_mfma_f32_32x32x16_f16(a,b,c,0,0,0)
#define MFMA16(a,b,c) __builtin_amdgcn_mfma_f32_16x16x32_f16(a,b,c,0,0,0)

DEV f32x16 zero16(){
  f32x16 v;
  #pragma unroll
  for (int i=0;i<16;i++) v[i]=0.f;
  return v;
}
DEV f32x4 zero4(){
  f32x4 v;
  #pragma unroll
  for (int i=0;i<4;i++) v[i]=0.f;
  return v;
}

// fast exact-GELU: erf via Abramowitz-Stegun 7.1.26 (|err| <= 1.5e-7)
DEV float gelu_f(float x){
  float z  = 0.70710678118654752440f * x;
  float az = fabsf(z);
  float t  = frcp(1.f + 0.3275911f*az);
  float poly = t*(0.254829592f + t*(-0.284496736f + t*(1.421413741f +
               t*(-1.453152027f + t*1.061405429f))));
  float e  = 1.f - poly*fexp2(-z*z*LOG2E);
  float er = (z < 0.f) ? -e : e;
  return 0.5f*x*(1.f + er);
}

DEV void pvar_body(const float* __restrict__ pw, float* __restrict__ partials,
                   char* smem, int id, int tid){
  int q = tid & 31, rg = tid >> 5;
  f32x4 s1 = zero4(), s2 = zero4();
  const float* p0 = pw + ((size_t)id*512 + rg)*128 + q*4;
  #pragma unroll 4
  for (int it=0; it<64; it++){
    f32x4 v = *(const f32x4*)(p0 + (size_t)it*1024);
    s1 += v; s2 += v*v;
  }
  f32x4* r1 = (f32x4*)smem; f32x4* r2 = r1 + 256;
  r1[tid] = s1; r2[tid] = s2;
  __syncthreads();
  if (tid < 64){
    int qq = tid & 31;
    f32x4* rr = (tid >= 32) ? r2 : r1;
    f32x4 a = rr[qq];
    #pragma unroll
    for (int g=1; g<8; g++) a += rr[g*32+qq];
    *(f32x4*)(partials + (size_t)id*256 + ((tid>=32)?128:0) + qq*4) = a;
  }
}

// ======= K1: pvar (bids 0-1023, serpentine) || wtrans || X cast =======
__global__ __launch_bounds__(256) void k1_prep(const float* __restrict__ wq, f16* __restrict__ wqT,
                                               const float* __restrict__ wo, f16* __restrict__ woT,
                                               const float* __restrict__ X, f16* __restrict__ Xh,
                                               const float* __restrict__ pw, float* __restrict__ partials){
  __shared__ char sm[8192];
  int bid = blockIdx.x, tid = threadIdx.x;
  if (bid < 1024){
    pvar_body(pw, partials, sm, 1023 - bid, tid);
    return;
  }
  if (bid >= 5344){
    size_t i0 = (size_t)(bid - 5344)*2048 + (size_t)tid*8;
    f32x4 a = *(const f32x4*)(X + i0);
    f32x4 b = *(const f32x4*)(X + i0 + 4);
    f16x8 o;
    #pragma unroll
    for (int e=0;e<4;e++){ o[e] = (f16)a[e]; o[4+e] = (f16)b[e]; }
    *(f16x8*)(Xh + i0) = o;
    return;
  }
  float (*t)[33] = (float(*)[33])sm;
  int wb_ = bid - 1024;
  int tx = tid & 31, ty = tid >> 5;
  const float* src; f16* dst; int N, x, y;
  if (wb_ < 2016){ src = wq; dst = wqT; N = 1344; x = wb_ % 48; y = wb_ / 48; }
  else { int b2 = wb_ - 2016; src = wo; dst = woT; N = 1536; x = b2 % 48; y = b2 / 48; }
  int k0 = x*32, n0 = y*32;
  #pragma unroll
  for (int i=0;i<4;i++){ int r = ty+8*i; t[r][tx] = src[(size_t)(k0+r)*N + n0+tx]; }
  __syncthreads();
  #pragma unroll
  for (int i=0;i<4;i++){ int r = ty+8*i; dst[(size_t)(n0+r)*1536 + k0+tx] = (f16)t[tx][r]; }
}

// ================= finvar (+ zero attn counters) =================
__global__ __launch_bounds__(256) void finvar_k(const float* __restrict__ partials,
    const float* __restrict__ rvar, const float* __restrict__ gamma,
    const float* __restrict__ beta, float* __restrict__ sg, float* __restrict__ sb,
    u32* __restrict__ cnt){
  __shared__ float sh[256];
  int tid = threadIdx.x;
  cnt[tid] = 0u;                      // re-zeroed every call, before attn
  int c = tid & 127, wh = tid >> 7;
  float acc = 0.f;
  #pragma unroll 8
  for (int i=0;i<1024;i++) acc += partials[i*256 + wh*128 + c];
  sh[tid] = acc;
  __syncthreads();
  if (tid < 128){
    float s1 = sh[tid], s2 = sh[tid+128];
    const float Minv = 1.f/524288.f;
    float m = s1*Minv;
    float var = s2*Minv - m*m;
    float rv = rvar[tid]*0.9f + 0.1f*var;
    sg[tid] = rsqrtf(rv + 1e-5f)*gamma[tid];
    sb[tid] = beta[tid];
  }
}

// ======== fused qkv-GEMM + LayerNorm: BM=128, BN=NF*32, double-buffered, setprio(T5) ========
template<int NF>
DEV void qkvln_body(const f16* __restrict__ A, const f16* __restrict__ WT, int nbase,
                    const float* __restrict__ lnw, const float* __restrict__ lnb,
                    f16* __restrict__ d0, size_t bstride,
                    char* lds, int mt, int tid){
  const int BN = NF*32;
  int mb = mt*128;
  int w = tid>>6, lane = tid&63, li = lane&31, h = lane>>5;
  int srow = lane>>3, sc = lane&7;
  f32x16 acc[NF];
  #pragma unroll
  for (int nf=0;nf<NF;nf++) acc[nf] = zero16();

#define QL_STAGE(buf, kt_) do { \
    char* ad = lds + (buf)*40960; \
    _Pragma("unroll") \
    for (int s=0;s<4;s++){ \
      int slot = w*4+s; int row = slot*8 + srow; int cs = sc ^ (srow&7); \
      g2l16(A + (size_t)(mb+row)*DMODEL + (kt_)*64 + cs*8, ad + slot*1024); \
    } \
    char* bd = lds + (buf)*40960 + 16384; \
    _Pragma("unroll") \
    for (int s=0;s<NF;s++){ \
      int slot = w*NF+s; int row = slot*8 + srow; int cs = sc ^ (srow&7); \
      g2l16(WT + (size_t)(nbase+row)*DMODEL + (kt_)*64 + cs*8, bd + slot*1024); \
    } } while(0)

  QL_STAGE(0,0);
  __syncthreads();
  for (int kt=0; kt<24; kt++){
    int cur = kt&1;
    if (kt<23) QL_STAGE(cur^1, kt+1);
    const char* ad = lds + cur*40960;
    const char* bd = lds + cur*40960 + 16384;
    __builtin_amdgcn_s_setprio(1);
    #pragma unroll
    for (int ks=0; ks<4; ks++){
      int cso = ((2*ks+h) ^ (li&7))*16;
      f16x8 af = *(const f16x8*)(ad + (w*32 + li)*128 + cso);
      #pragma unroll
      for (int nf=0; nf<NF; nf++){
        f16x8 bf = *(const f16x8*)(bd + (nf*32 + li)*128 + cso);
        acc[nf] = MFMA32(af, bf, acc[nf]);
      }
    }
    __builtin_amdgcn_s_setprio(0);
    __syncthreads();
  }

  float Wc[NF], Bc[NF];
  #pragma unroll
  for (int nf=0;nf<NF;nf++){ Wc[nf] = lnw[nf*32+li]; Bc[nf] = lnb[nf*32+li]; }
  const float invBN = 1.f/(float)BN;
  #pragma unroll
  for (int rr=0; rr<16; rr++){
    float s = 0.f;
    #pragma unroll
    for (int nf=0;nf<NF;nf++) s += acc[nf][rr];
    #pragma unroll
    for (int d=16; d>=1; d>>=1) s += __shfl_xor(s, d);
    float mu = s*invBN;
    float vv = 0.f;
    #pragma unroll
    for (int nf=0;nf<NF;nf++){ float dd = acc[nf][rr]-mu; vv += dd*dd; }
    #pragma unroll
    for (int d=16; d>=1; d>>=1) vv += __shfl_xor(vv, d);
    float istd = rsqrtf(vv*invBN + 1e-5f);
    int r = (rr&3) + 8*(rr>>2) + 4*h;
    int m = mb + w*32 + r;
    int bb = m >> 11, nseq = m & 2047;
    f16* drow = d0 + (size_t)bb*bstride + (size_t)nseq*BN;
    #pragma unroll
    for (int nf=0;nf<NF;nf++)
      drow[nf*32+li] = (f16)((acc[nf][rr]-mu)*istd*Wc[nf] + Bc[nf]);
  }
#undef QL_STAGE
}

// bias_gemm body: f32 pairwise read, no LDS
DEV void bias_body(const float* __restrict__ pw,
    const float* __restrict__ sg, const float* __restrict__ sb,
    const float* __restrict__ wb, f16* __restrict__ biasc, int bias_id, int tid){
  int w = tid>>6, lane = tid&63;
  int il = lane&15, kg = lane>>4;
  f16x8 bw[4];
  float sgr[32], sbr[32];
  #pragma unroll
  for (int t=0;t<4;t++)
    #pragma unroll
    for (int e=0;e<8;e++){
      int k = t*32 + kg*8 + e;
      bw[t][e] = (f16)((il<8) ? wb[k*8 + il] : 0.f);
      sgr[t*8+e] = sg[k];
      sbr[t*8+e] = sb[k];
    }
  for (int it=0; it<8; it++){
    int tile = bias_id*4 + w + it*4096;
    size_t rg = (size_t)tile*16 + il;
    f32x4 acc = zero4();
    #pragma unroll
    for (int t=0;t<4;t++){
      const float* sp = pw + rg*128 + t*32 + kg*8;
      f32x4 v0 = *(const f32x4*)sp;
      f32x4 v1 = *(const f32x4*)(sp+4);
      f16x8 af;
      #pragma unroll
      for (int e=0;e<4;e++) af[e]   = (f16)gelu_f(v0[e]*sgr[t*8+e]   + sbr[t*8+e]);
      #pragma unroll
      for (int e=0;e<4;e++) af[4+e] = (f16)gelu_f(v1[e]*sgr[t*8+4+e] + sbr[t*8+4+e]);
      acc = MFMA16(af, bw[t], acc);
    }
    if (il < 8){
      #pragma unroll
      for (int r=0;r<4;r++){
        size_t rr = (size_t)tile*16 + kg*4 + r;
        int bb = (int)(rr >> 18);
        int rem = (int)(rr & 262143);
        int ii = rem >> 9, jj = rem & 511;
        biasc[(((size_t)(bb*8 + il)*512) + ii)*512 + jj] = (f16)acc[r];
      }
    }
  }
}

// ========== K2': qkvln GEMM (bids 0-319, front, XCD-chunked) || bias_gemm (320-1343) ==========
__global__ __launch_bounds__(256,2) void k2_qkvln_bias(const f16* __restrict__ Xh,
    const f16* __restrict__ WT,
    const float* __restrict__ qw, const float* __restrict__ qb,
    const float* __restrict__ kw, const float* __restrict__ kb,
    const float* __restrict__ vw, const float* __restrict__ vb,
    f16* __restrict__ Q, f16* __restrict__ K, f16* __restrict__ V,
    const float* __restrict__ pw, const float* __restrict__ sg, const float* __restrict__ sb,
    const float* __restrict__ wb, f16* __restrict__ biasc){
  __shared__ char smem[81920];
  int bid = blockIdx.x, tid = threadIdx.x;
  if (bid < 320){
    int l = (bid&7)*40 + (bid>>3);           // XCD-chunked (320 = 8*40), seg-major
    int seg = l >> 5, mt = l & 31;
    if (seg < 8)
      qkvln_body<4>(Xh, WT, seg*128, qw, qb, Q + (size_t)seg*SEQ*DQK,
                    (size_t)NHEADS*SEQ*DQK, smem, mt, tid);
    else if (seg == 8)
      qkvln_body<4>(Xh, WT, 1024, kw, kb, K, (size_t)SEQ*DQK, smem, mt, tid);
    else
      qkvln_body<6>(Xh, WT, 1152, vw, vb, V, (size_t)SEQ*DVV, smem, mt, tid);
  } else {
    bias_body(pw, sg, sb, wb, biasc, bid - 320, tid);
  }
}

// ================= K4: vtrans only (768 blocks, small LDS, high occupancy) =================
__global__ __launch_bounds__(256) void k4_vtrans(const f16* __restrict__ V, f16* __restrict__ VT){
  __shared__ f16 t[32][33];
  int id = blockIdx.x, tid = threadIdx.x;
  int b = id / 384, rem = id - b*384;
  int d0 = (rem % 6)*32, j0 = (rem / 6)*32;
  int tx = tid & 31, ty = tid >> 5;
  #pragma unroll
  for (int i=0;i<4;i++){ int r = ty+8*i; t[r][tx] = V[((size_t)b*SEQ + j0+r)*DVV + d0+tx]; }
  __syncthreads();
  #pragma unroll
  for (int i=0;i<4;i++){ int r = ty+8*i; VT[((size_t)b*DVV + d0+r)*SEQ + j0+tx] = t[tx][r]; }
}

// ===== K5: fused attention, j-split (grid 512, 2 blocks/CU), fused atomic-tail combine =====
// finisher-order flag overlaid in lds (no extra static LDS: stays 81920 -> 2 blocks/CU)
__global__ __launch_bounds__(256,2) void attn(const f16* __restrict__ Q, const f16* __restrict__ K,
                                              const f16* __restrict__ VT, const f16* __restrict__ biasc,
                                              f16* __restrict__ Opart, float* __restrict__ Ls,
                                              f16* __restrict__ AO, u32* __restrict__ cnt){
  __shared__ char lds[81920];
  int bid = blockIdx.x;
  int half = bid & 1, bgqt = bid >> 1;
  int bg = bgqt & 15, qt = bgqt >> 4;
  int b = bg >> 3;
  int tid = threadIdx.x;
  int w = tid >> 6, lane = tid & 63;
  int li = lane & 31, h = lane >> 5;

  const f16* Qb = Q  + (size_t)bg*SEQ*DQK;
  const f16* Kb = K  + (size_t)b*SEQ*DQK;
  const f16* Vb = VT + (size_t)b*DVV*SEQ;

  int qrow = qt*128 + w*32 + li;
  f16x8 qf[8];
  #pragma unroll
  for (int ks=0; ks<8; ks++)
    qf[ks] = *(const f16x8*)(Qb + (size_t)qrow*DQK + ks*16 + h*8);

  const f16* brow = biasc + ((size_t)bg*512 + (qrow>>2))*512;

  f32x16 oacc[6];
  #pragma unroll
  for (int nf=0;nf<6;nf++) oacc[nf] = zero16();
  float lsum = 0.f;

  int kl_row = lane >> 4, kl_c = lane & 15;
  int vl_row = lane >> 3, vl_c = lane & 7;

#define STAGE(buf, jt_) do { \
    char* kd = lds + (buf)*40960; \
    const f16* ksrc = Kb + (size_t)(jt_)*64*DQK; \
    _Pragma("unroll") \
    for (int s=0;s<4;s++){ \
      int slot = w*4+s; int jr = slot*4 + kl_row; int cs = kl_c ^ (jr&7); \
      g2l16(ksrc + (size_t)jr*DQK + cs*8, kd + slot*1024); \
    } \
    char* vd = lds + (buf)*40960 + 16384; \
    _Pragma("unroll") \
    for (int s=0;s<6;s++){ \
      int slot = w*6+s; int dvr = slot*8 + vl_row; int cs = vl_c ^ (dvr&7); \
      g2l16(Vb + (size_t)dvr*SEQ + (size_t)(jt_)*64 + cs*8, vd + slot*1024); \
    } } while(0)

  int jt0 = half*16;
  STAGE(0, jt0);

  const float CS = SCALEQK * (2.f*LOG2E/5.f);
  const float CB = 2.f*LOG2E/5.f;
  const float CP = 5.f*LOG2E;

  for (int jj=0; jj<16; jj++){
    int jt = jt0 + jj;
    int cur = jj & 1;
    __syncthreads();
    if (jj < 15) STAGE(cur^1, jt+1);
    const char* kb_ = lds + cur*40960;
    const char* vb_ = lds + cur*40960 + 16384;

    f32x16 s0 = zero16(), s1 = zero16();
    __builtin_amdgcn_s_setprio(1);
    #pragma unroll
    for (int ks=0; ks<8; ks++){
      int cso = ((2*ks + h) ^ (li&7))*16;
      f16x8 kf0 = *(const f16x8*)(kb_ + (     li)*256 + cso);
      f16x8 kf1 = *(const f16x8*)(kb_ + (32 + li)*256 + cso);
      s0 = MFMA32(kf0, qf[ks], s0);
      s1 = MFMA32(kf1, qf[ks], s1);
    }
    __builtin_amdgcn_s_setprio(0);

    f16x8 pa[2][2];
    #pragma unroll
    for (int sub=0; sub<2; sub++){
      const f32x16& sacc = sub ? s1 : s0;
      int jb4 = jt*16 + sub*8;
      f16x8 bv = *(const f16x8*)(brow + jb4);
      float bt[4];
      #pragma unroll
      for (int q=0;q<4;q++){
        float b0 = (float)bv[2*q], b1 = (float)bv[2*q+1];
        bt[q] = (h ? b1 : b0) * CB;
      }
      float p[16], xp[16];
      #pragma unroll
      for (int r=0;r<16;r++){
        float u2 = sacc[r]*CS + bt[r>>2];
        float E  = fexp2(u2);
        float tn = 1.f - 2.f*frcp(E + 1.f);
        float pr = fexp2(tn * CP);
        p[r] = pr;
        lsum += pr;
      }
      #pragma unroll
      for (int r=0;r<16;r++) xp[r] = __shfl_xor(p[r], 32);
      #pragma unroll
      for (int ks2=0; ks2<2; ks2++){
        #pragma unroll
        for (int e=0;e<4;e++) pa[sub][ks2][e] = (f16)(h ? xp[8*ks2+4+e] : p[8*ks2+e]);
        #pragma unroll
        for (int e=4;e<8;e++) pa[sub][ks2][e] = (f16)(h ? p[8*ks2+e]    : xp[8*ks2+e-4]);
      }
    }
    __builtin_amdgcn_s_setprio(1);
    #pragma unroll
    for (int sub=0; sub<2; sub++)
      #pragma unroll
      for (int ks2=0; ks2<2; ks2++)
        #pragma unroll
        for (int nf=0; nf<6; nf++){
          int dvr = nf*32 + li;
          int cj = (sub*4 + 2*ks2 + h) ^ (dvr&7);
          f16x8 vf = *(const f16x8*)(vb_ + dvr*128 + cj*16);
          oacc[nf] = MFMA32(pa[sub][ks2], vf, oacc[nf]);
        }
    __builtin_amdgcn_s_setprio(0);
  }
  f16* Ob = Opart + (size_t)(bgqt*2 + half)*128*192;
  #pragma unroll
  for (int nf=0; nf<6; nf++)
    #pragma unroll
    for (int r=0;r<16;r++){
      int il = (r&3) + 8*(r>>2) + 4*h;
      Ob[(size_t)(w*32 + il)*192 + nf*32 + li] = (f16)oacc[nf][r];
    }
  float ltot = lsum + __shfl_xor(lsum, 32);
  if (h == 0) Ls[(size_t)(bgqt*2 + half)*128 + w*32 + li] = ltot;

  // ---- fused combine: second finisher for this bgqt normalizes & writes AO ----
  __syncthreads();                               // lds staging dead; safe to overlay
  volatile u32* ordp = (volatile u32*)lds;
  __threadfence();                               // release: flush Opart/Ls device-wide
  if (tid == 0) *ordp = atomicAdd(&cnt[bgqt], 1u);
  __syncthreads();
  if (*ordp == 1u){
    __threadfence();                             // acquire: see other block's writes
    int row = tid >> 1, cs0 = (tid & 1)*96;
    float l0 = Ls[(size_t)(bgqt*2 + 0)*128 + row];
    float l1 = Ls[(size_t)(bgqt*2 + 1)*128 + row];
    float linv = 1.f / (l0 + l1);
    const f16* P0 = Opart + ((size_t)(bgqt*2 + 0)*128 + row)*192 + cs0;
    const f16* P1 = Opart + ((size_t)(bgqt*2 + 1)*128 + row)*192 + cs0;
    int g = bg & 7;
    int n = qt*128 + row;
    f16* dst = AO + ((size_t)(b*SEQ + n)*NHEADS + g)*DVV + cs0;
    #pragma unroll
    for (int j=0;j<12;j++){
      f16x8 a = *(const f16x8*)(P0 + 8*j);
      f16x8 c = *(const f16x8*)(P1 + 8*j);
      f16x8 o;
      #pragma unroll
      for (int e=0;e<8;e++) o[e] = (f16)(((float)a[e] + (float)c[e]) * linv);
      *(f16x8*)(dst + 8*j) = o;
    }
  }
#undef STAGE
}

// ================= K6: out GEMM (256x64 tile, XCD-chunked) =================
DEV void gemm256_body(const f16* __restrict__ A, const f16* __restrict__ WT,
                      float* __restrict__ C, int ldc, const float* __restrict__ bo,
                      char* lds, int bx, int by, int tid){
  int nb = bx*64, mb = by*256;
  int w = tid>>6, lane = tid&63, li = lane&31, h = lane>>5;
  int srow = lane>>3, sc = lane&7;
  f32x16 acc[2][2];
  acc[0][0]=zero16(); acc[0][1]=zero16(); acc[1][0]=zero16(); acc[1][1]=zero16();

#define G_STAGE(buf, kt_) do { \
    char* ad = lds + (buf)*40960; \
    _Pragma("unroll") \
    for (int s=0;s<8;s++){ \
      int slot = w*8+s; int mlr = slot*8 + srow; int cs = sc ^ (srow&7); \
      g2l16(A + (size_t)(mb+mlr)*DMODEL + (kt_)*64 + cs*8, ad + slot*1024); \
    } \
    char* bd = lds + (buf)*40960 + 32768; \
    _Pragma("unroll") \
    for (int s=0;s<2;s++){ \
      int slot = w*2+s; int nl = slot*8 + srow; int cs = sc ^ (srow&7); \
      g2l16(WT + (size_t)(nb+nl)*DMODEL + (kt_)*64 + cs*8, bd + slot*1024); \
    } } while(0)

  G_STAGE(0,0);
  __syncthreads();
  for (int kt=0; kt<24; kt++){
    int cur = kt&1;
    if (kt<23) G_STAGE(cur^1, kt+1);
    const char* ad = lds + cur*40960;
    const char* bd = lds + cur*40960 + 32768;
    #pragma unroll
    for (int ks=0; ks<4; ks++){
      int cso = ((2*ks+h) ^ (li&7))*16;
      f16x8 a0 = *(const f16x8*)(ad + (w*64      + li)*128 + cso);
      f16x8 a1 = *(const f16x8*)(ad + (w*64 + 32 + li)*128 + cso);
      f16x8 b0 = *(const f16x8*)(bd + (           li)*128 + cso);
      f16x8 b1 = *(const f16x8*)(bd + (      32 + li)*128 + cso);
      acc[0][0] = MFMA32(a0, b0, acc[0][0]);
      acc[0][1] = MFMA32(a0, b1, acc[0][1]);
      acc[1][0] = MFMA32(a1, b0, acc[1][0]);
      acc[1][1] = MFMA32(a1, b1, acc[1][1]);
    }
    __syncthreads();
  }
  float bo0 = bo ? bo[nb+li] : 0.f, bo1 = bo ? bo[nb+32+li] : 0.f;
  #pragma unroll
  for (int mi=0; mi<2; mi++)
    #pragma unroll
    for (int nf=0; nf<2; nf++)
      #pragma unroll
      for (int r=0;r<16;r++){
        int m = mb + w*64 + mi*32 + (r&3) + 8*(r>>2) + 4*h;
        int n = nb + nf*32 + li;
        C[(size_t)m*ldc + n] = acc[mi][nf][r] + (nf ? bo1 : bo0);
      }
#undef G_STAGE
}

__global__ __launch_bounds__(256,2) void out_gemm(const f16* __restrict__ A, const f16* __restrict__ WT,
                                                  const float* __restrict__ bo, float* __restrict__ out){
  __shared__ char lds[81920];
  int bid = blockIdx.x, tid = threadIdx.x;
  int l = (bid&7)*48 + (bid>>3);
  gemm256_body(A, WT, out, DMODEL, bo, lds, l%24, l/24, tid);
}

extern "C" void kernel_launch(void* const* d_in, const int* in_sizes, int n_in,
                              void* d_out, int out_size, void* d_ws, size_t ws_size,
                              hipStream_t stream) {
  (void)in_sizes; (void)n_in; (void)out_size; (void)ws_size;
  const float* x        = (const float*)d_in[0];
  const float* pairwise = (const float*)d_in[1];
  const float* w_qkv    = (const float*)d_in[2];
  const float* q_w      = (const float*)d_in[3];
  const float* q_b      = (const float*)d_in[4];
  const float* k_w      = (const float*)d_in[5];
  const float* k_b      = (const float*)d_in[6];
  const float* v_w      = (const float*)d_in[7];
  const float* v_b      = (const float*)d_in[8];
  const float* bgamma   = (const float*)d_in[9];
  const float* bbeta    = (const float*)d_in[10];
  const float* brvar    = (const float*)d_in[11];
  const float* w_bias   = (const float*)d_in[12];
  const float* w_out    = (const float*)d_in[13];
  const float* b_out    = (const float*)d_in[14];
  float* out = (float*)d_out;

  char* ws = (char*)d_ws;
  f16*   wqkvT = (f16*)(ws + OFF_WQKVT);
  f16*   woutT = (f16*)(ws + OFF_WOUTT);
  f16*   Xh    = (f16*)(ws + OFF_XH);
  f16*   Qh    = (f16*)(ws + OFF_Q);
  f16*   Kh    = (f16*)(ws + OFF_K);
  f16*   Vh    = (f16*)(ws + OFF_V);
  f16*   VTh   = (f16*)(ws + OFF_VT);
  float* part  = (float*)(ws + OFF_PART);
  float* sg    = (float*)(ws + OFF_SG);
  float* sb    = sg + 128;
  f16*   biasc = (f16*)(ws + OFF_BIASC);
  f16*   AOh   = (f16*)(ws + OFF_AO);
  f16*   Opart = (f16*)(ws + OFF_OP);
  float* Lsw   = (float*)(ws + OFF_LS);
  u32*   cnt   = (u32*)(ws + OFF_CNT);

  k1_prep<<<8416, 256, 0, stream>>>(w_qkv, wqkvT, w_out, woutT, x, Xh, pairwise, part);
  finvar_k<<<1, 256, 0, stream>>>(part, brvar, bgamma, bbeta, sg, sb, cnt);
  k2_qkvln_bias<<<1344, 256, 0, stream>>>(Xh, wqkvT, q_w,q_b,k_w,k_b,v_w,v_b,
                                          Qh, Kh, Vh, pairwise, sg, sb, w_bias, biasc);
  k4_vtrans<<<768, 256, 0, stream>>>(Vh, VTh);
  attn<<<512, 256, 0, stream>>>(Qh, Kh, VTh, biasc, Opart, Lsw, AOh, cnt);
  out_gemm<<<384, 256, 0, stream>>>(AOh, woutT, b_out, out);
}

// Round 22
// 309.410 us; speedup vs baseline: 1.4771x; 1.3548x over previous
//
#include <hip/hip_runtime.h>
#include <math.h>

typedef _Float16 f16;
typedef unsigned int u32;
typedef __attribute__((ext_vector_type(8))) f16 f16x8;
typedef __attribute__((ext_vector_type(4))) f16 f16x4;
typedef __attribute__((ext_vector_type(4))) float f32x4;
typedef __attribute__((ext_vector_type(16))) float f32x16;

#define DEV static __device__ __forceinline__

#define SEQ 2048
#define DMODEL 1536
#define NHEADS 8
#define DQK 128
#define DVV 192
#define QKVW 1344
#define SCALEQK 0.08838834764831845f
#define LOG2E 1.4426950408889634f

// ---------------- workspace layout (bytes) ----------------
#define OFF_WQKVT 0ull
#define OFF_WOUTT 4128768ull
#define OFF_XH    8847360ull
#define OFF_Q     21430272ull
#define OFF_K     29818880ull
#define OFF_V     30867456ull
#define OFF_VT    32440320ull
#define OFF_PART  34013184ull
#define OFF_SG    35061760ull
#define OFF_BIASC 35062784ull
#define OFF_AO    43451392ull
#define OFF_OP    56034304ull          // f16 [256][2][128][192] = 25,165,824
#define OFF_LS    81200128ull          // f32 [256][2][128] = 262,144

DEV float fexp2(float x){
#if __has_builtin(__builtin_amdgcn_exp2f)
  return __builtin_amdgcn_exp2f(x);
#else
  return exp2f(x);
#endif
}
DEV float frcp(float x){
#if __has_builtin(__builtin_amdgcn_rcpf)
  return __builtin_amdgcn_rcpf(x);
#else
  return 1.0f/x;
#endif
}

typedef u32 __attribute__((address_space(1))) u32g;
typedef u32 __attribute__((address_space(3))) u32l;
DEV void g2l16(const void* g, void* l){
  __builtin_amdgcn_global_load_lds((const u32g*)g, (u32l*)l, 16, 0, 0);
}

#define MFMA32(a,b,c) __builtin_amdgcn_mfma_f32_32x32x16_f16(a,b,c,0,0,0)
#define MFMA16(a,b,c) __builtin_amdgcn_mfma_f32_16x16x32_f16(a,b,c,0,0,0)

DEV f32x16 zero16(){
  f32x16 v;
  #pragma unroll
  for (int i=0;i<16;i++) v[i]=0.f;
  return v;
}
DEV f32x4 zero4(){
  f32x4 v;
  #pragma unroll
  for (int i=0;i<4;i++) v[i]=0.f;
  return v;
}

// fast exact-GELU: erf via Abramowitz-Stegun 7.1.26 (|err| <= 1.5e-7)
DEV float gelu_f(float x){
  float z  = 0.70710678118654752440f * x;
  float az = fabsf(z);
  float t  = frcp(1.f + 0.3275911f*az);
  float poly = t*(0.254829592f + t*(-0.284496736f + t*(1.421413741f +
               t*(-1.453152027f + t*1.061405429f))));
  float e  = 1.f - poly*fexp2(-z*z*LOG2E);
  float er = (z < 0.f) ? -e : e;
  return 0.5f*x*(1.f + er);
}

DEV void pvar_body(const float* __restrict__ pw, float* __restrict__ partials,
                   char* smem, int id, int tid){
  int q = tid & 31, rg = tid >> 5;
  f32x4 s1 = zero4(), s2 = zero4();
  const float* p0 = pw + ((size_t)id*512 + rg)*128 + q*4;
  #pragma unroll 4
  for (int it=0; it<64; it++){
    f32x4 v = *(const f32x4*)(p0 + (size_t)it*1024);
    s1 += v; s2 += v*v;
  }
  f32x4* r1 = (f32x4*)smem; f32x4* r2 = r1 + 256;
  r1[tid] = s1; r2[tid] = s2;
  __syncthreads();
  if (tid < 64){
    int qq = tid & 31;
    f32x4* rr = (tid >= 32) ? r2 : r1;
    f32x4 a = rr[qq];
    #pragma unroll
    for (int g=1; g<8; g++) a += rr[g*32+qq];
    *(f32x4*)(partials + (size_t)id*256 + ((tid>=32)?128:0) + qq*4) = a;
  }
}

// ======= K1: pvar (bids 0-1023, serpentine) || wtrans || X cast =======
__global__ __launch_bounds__(256) void k1_prep(const float* __restrict__ wq, f16* __restrict__ wqT,
                                               const float* __restrict__ wo, f16* __restrict__ woT,
                                               const float* __restrict__ X, f16* __restrict__ Xh,
                                               const float* __restrict__ pw, float* __restrict__ partials){
  __shared__ char sm[8192];
  int bid = blockIdx.x, tid = threadIdx.x;
  if (bid < 1024){
    pvar_body(pw, partials, sm, 1023 - bid, tid);
    return;
  }
  if (bid >= 5344){
    size_t i0 = (size_t)(bid - 5344)*2048 + (size_t)tid*8;
    f32x4 a = *(const f32x4*)(X + i0);
    f32x4 b = *(const f32x4*)(X + i0 + 4);
    f16x8 o;
    #pragma unroll
    for (int e=0;e<4;e++){ o[e] = (f16)a[e]; o[4+e] = (f16)b[e]; }
    *(f16x8*)(Xh + i0) = o;
    return;
  }
  float (*t)[33] = (float(*)[33])sm;
  int wb_ = bid - 1024;
  int tx = tid & 31, ty = tid >> 5;
  const float* src; f16* dst; int N, x, y;
  if (wb_ < 2016){ src = wq; dst = wqT; N = 1344; x = wb_ % 48; y = wb_ / 48; }
  else { int b2 = wb_ - 2016; src = wo; dst = woT; N = 1536; x = b2 % 48; y = b2 / 48; }
  int k0 = x*32, n0 = y*32;
  #pragma unroll
  for (int i=0;i<4;i++){ int r = ty+8*i; t[r][tx] = src[(size_t)(k0+r)*N + n0+tx]; }
  __syncthreads();
  #pragma unroll
  for (int i=0;i<4;i++){ int r = ty+8*i; dst[(size_t)(n0+r)*1536 + k0+tx] = (f16)t[tx][r]; }
}

// ================= finvar =================
__global__ __launch_bounds__(256) void finvar_k(const float* __restrict__ partials,
    const float* __restrict__ rvar, const float* __restrict__ gamma,
    const float* __restrict__ beta, float* __restrict__ sg, float* __restrict__ sb){
  __shared__ float sh[256];
  int tid = threadIdx.x;
  int c = tid & 127, wh = tid >> 7;
  float acc = 0.f;
  #pragma unroll 8
  for (int i=0;i<1024;i++) acc += partials[i*256 + wh*128 + c];
  sh[tid] = acc;
  __syncthreads();
  if (tid < 128){
    float s1 = sh[tid], s2 = sh[tid+128];
    const float Minv = 1.f/524288.f;
    float m = s1*Minv;
    float var = s2*Minv - m*m;
    float rv = rvar[tid]*0.9f + 0.1f*var;
    sg[tid] = rsqrtf(rv + 1e-5f)*gamma[tid];
    sb[tid] = beta[tid];
  }
}

// ======== fused qkv-GEMM + LayerNorm: BM=128, BN=NF*32, double-buffered, setprio(T5) ========
template<int NF>
DEV void qkvln_body(const f16* __restrict__ A, const f16* __restrict__ WT, int nbase,
                    const float* __restrict__ lnw, const float* __restrict__ lnb,
                    f16* __restrict__ d0, size_t bstride,
                    char* lds, int mt, int tid){
  const int BN = NF*32;
  int mb = mt*128;
  int w = tid>>6, lane = tid&63, li = lane&31, h = lane>>5;
  int srow = lane>>3, sc = lane&7;
  f32x16 acc[NF];
  #pragma unroll
  for (int nf=0;nf<NF;nf++) acc[nf] = zero16();

#define QL_STAGE(buf, kt_) do { \
    char* ad = lds + (buf)*40960; \
    _Pragma("unroll") \
    for (int s=0;s<4;s++){ \
      int slot = w*4+s; int row = slot*8 + srow; int cs = sc ^ (srow&7); \
      g2l16(A + (size_t)(mb+row)*DMODEL + (kt_)*64 + cs*8, ad + slot*1024); \
    } \
    char* bd = lds + (buf)*40960 + 16384; \
    _Pragma("unroll") \
    for (int s=0;s<NF;s++){ \
      int slot = w*NF+s; int row = slot*8 + srow; int cs = sc ^ (srow&7); \
      g2l16(WT + (size_t)(nbase+row)*DMODEL + (kt_)*64 + cs*8, bd + slot*1024); \
    } } while(0)

  QL_STAGE(0,0);
  __syncthreads();
  for (int kt=0; kt<24; kt++){
    int cur = kt&1;
    if (kt<23) QL_STAGE(cur^1, kt+1);
    const char* ad = lds + cur*40960;
    const char* bd = lds + cur*40960 + 16384;
    __builtin_amdgcn_s_setprio(1);
    #pragma unroll
    for (int ks=0; ks<4; ks++){
      int cso = ((2*ks+h) ^ (li&7))*16;
      f16x8 af = *(const f16x8*)(ad + (w*32 + li)*128 + cso);
      #pragma unroll
      for (int nf=0; nf<NF; nf++){
        f16x8 bf = *(const f16x8*)(bd + (nf*32 + li)*128 + cso);
        acc[nf] = MFMA32(af, bf, acc[nf]);
      }
    }
    __builtin_amdgcn_s_setprio(0);
    __syncthreads();
  }

  float Wc[NF], Bc[NF];
  #pragma unroll
  for (int nf=0;nf<NF;nf++){ Wc[nf] = lnw[nf*32+li]; Bc[nf] = lnb[nf*32+li]; }
  const float invBN = 1.f/(float)BN;
  #pragma unroll
  for (int rr=0; rr<16; rr++){
    float s = 0.f;
    #pragma unroll
    for (int nf=0;nf<NF;nf++) s += acc[nf][rr];
    #pragma unroll
    for (int d=16; d>=1; d>>=1) s += __shfl_xor(s, d);
    float mu = s*invBN;
    float vv = 0.f;
    #pragma unroll
    for (int nf=0;nf<NF;nf++){ float dd = acc[nf][rr]-mu; vv += dd*dd; }
    #pragma unroll
    for (int d=16; d>=1; d>>=1) vv += __shfl_xor(vv, d);
    float istd = rsqrtf(vv*invBN + 1e-5f);
    int r = (rr&3) + 8*(rr>>2) + 4*h;
    int m = mb + w*32 + r;
    int bb = m >> 11, nseq = m & 2047;
    f16* drow = d0 + (size_t)bb*bstride + (size_t)nseq*BN;
    #pragma unroll
    for (int nf=0;nf<NF;nf++)
      drow[nf*32+li] = (f16)((acc[nf][rr]-mu)*istd*Wc[nf] + Bc[nf]);
  }
#undef QL_STAGE
}

// bias_gemm body: f32 pairwise read, no LDS
DEV void bias_body(const float* __restrict__ pw,
    const float* __restrict__ sg, const float* __restrict__ sb,
    const float* __restrict__ wb, f16* __restrict__ biasc, int bias_id, int tid){
  int w = tid>>6, lane = tid&63;
  int il = lane&15, kg = lane>>4;
  f16x8 bw[4];
  float sgr[32], sbr[32];
  #pragma unroll
  for (int t=0;t<4;t++)
    #pragma unroll
    for (int e=0;e<8;e++){
      int k = t*32 + kg*8 + e;
      bw[t][e] = (f16)((il<8) ? wb[k*8 + il] : 0.f);
      sgr[t*8+e] = sg[k];
      sbr[t*8+e] = sb[k];
    }
  for (int it=0; it<8; it++){
    int tile = bias_id*4 + w + it*4096;
    size_t rg = (size_t)tile*16 + il;
    f32x4 acc = zero4();
    #pragma unroll
    for (int t=0;t<4;t++){
      const float* sp = pw + rg*128 + t*32 + kg*8;
      f32x4 v0 = *(const f32x4*)sp;
      f32x4 v1 = *(const f32x4*)(sp+4);
      f16x8 af;
      #pragma unroll
      for (int e=0;e<4;e++) af[e]   = (f16)gelu_f(v0[e]*sgr[t*8+e]   + sbr[t*8+e]);
      #pragma unroll
      for (int e=0;e<4;e++) af[4+e] = (f16)gelu_f(v1[e]*sgr[t*8+4+e] + sbr[t*8+4+e]);
      acc = MFMA16(af, bw[t], acc);
    }
    if (il < 8){
      #pragma unroll
      for (int r=0;r<4;r++){
        size_t rr = (size_t)tile*16 + kg*4 + r;
        int bb = (int)(rr >> 18);
        int rem = (int)(rr & 262143);
        int ii = rem >> 9, jj = rem & 511;
        biasc[(((size_t)(bb*8 + il)*512) + ii)*512 + jj] = (f16)acc[r];
      }
    }
  }
}

// ========== K2': qkvln GEMM (bids 0-319, front, XCD-chunked) || bias_gemm (320-1343) ==========
__global__ __launch_bounds__(256,2) void k2_qkvln_bias(const f16* __restrict__ Xh,
    const f16* __restrict__ WT,
    const float* __restrict__ qw, const float* __restrict__ qb,
    const float* __restrict__ kw, const float* __restrict__ kb,
    const float* __restrict__ vw, const float* __restrict__ vb,
    f16* __restrict__ Q, f16* __restrict__ K, f16* __restrict__ V,
    const float* __restrict__ pw, const float* __restrict__ sg, const float* __restrict__ sb,
    const float* __restrict__ wb, f16* __restrict__ biasc){
  __shared__ char smem[81920];
  int bid = blockIdx.x, tid = threadIdx.x;
  if (bid < 320){
    int l = (bid&7)*40 + (bid>>3);           // XCD-chunked (320 = 8*40), seg-major
    int seg = l >> 5, mt = l & 31;
    if (seg < 8)
      qkvln_body<4>(Xh, WT, seg*128, qw, qb, Q + (size_t)seg*SEQ*DQK,
                    (size_t)NHEADS*SEQ*DQK, smem, mt, tid);
    else if (seg == 8)
      qkvln_body<4>(Xh, WT, 1024, kw, kb, K, (size_t)SEQ*DQK, smem, mt, tid);
    else
      qkvln_body<6>(Xh, WT, 1152, vw, vb, V, (size_t)SEQ*DVV, smem, mt, tid);
  } else {
    bias_body(pw, sg, sb, wb, biasc, bid - 320, tid);
  }
}

// ================= K4: vtrans only (768 blocks, small LDS, high occupancy) =================
__global__ __launch_bounds__(256) void k4_vtrans(const f16* __restrict__ V, f16* __restrict__ VT){
  __shared__ f16 t[32][33];
  int id = blockIdx.x, tid = threadIdx.x;
  int b = id / 384, rem = id - b*384;
  int d0 = (rem % 6)*32, j0 = (rem / 6)*32;
  int tx = tid & 31, ty = tid >> 5;
  #pragma unroll
  for (int i=0;i<4;i++){ int r = ty+8*i; t[r][tx] = V[((size_t)b*SEQ + j0+r)*DVV + d0+tx]; }
  __syncthreads();
  #pragma unroll
  for (int i=0;i<4;i++){ int r = ty+8*i; VT[((size_t)b*DVV + d0+r)*SEQ + j0+tx] = t[tx][r]; }
}

// ================= K5: fused attention, j-split (grid 512, 2 blocks/CU), setprio(T5) =================
__global__ __launch_bounds__(256,2) void attn(const f16* __restrict__ Q, const f16* __restrict__ K,
                                              const f16* __restrict__ VT, const f16* __restrict__ biasc,
                                              f16* __restrict__ Opart, float* __restrict__ Ls){
  __shared__ char lds[81920];
  int bid = blockIdx.x;
  int half = bid & 1, bgqt = bid >> 1;
  int bg = bgqt & 15, qt = bgqt >> 4;
  int b = bg >> 3;
  int tid = threadIdx.x;
  int w = tid >> 6, lane = tid & 63;
  int li = lane & 31, h = lane >> 5;

  const f16* Qb = Q  + (size_t)bg*SEQ*DQK;
  const f16* Kb = K  + (size_t)b*SEQ*DQK;
  const f16* Vb = VT + (size_t)b*DVV*SEQ;

  int qrow = qt*128 + w*32 + li;
  f16x8 qf[8];
  #pragma unroll
  for (int ks=0; ks<8; ks++)
    qf[ks] = *(const f16x8*)(Qb + (size_t)qrow*DQK + ks*16 + h*8);

  const f16* brow = biasc + ((size_t)bg*512 + (qrow>>2))*512;

  f32x16 oacc[6];
  #pragma unroll
  for (int nf=0;nf<6;nf++) oacc[nf] = zero16();
  float lsum = 0.f;

  int kl_row = lane >> 4, kl_c = lane & 15;
  int vl_row = lane >> 3, vl_c = lane & 7;

#define STAGE(buf, jt_) do { \
    char* kd = lds + (buf)*40960; \
    const f16* ksrc = Kb + (size_t)(jt_)*64*DQK; \
    _Pragma("unroll") \
    for (int s=0;s<4;s++){ \
      int slot = w*4+s; int jr = slot*4 + kl_row; int cs = kl_c ^ (jr&7); \
      g2l16(ksrc + (size_t)jr*DQK + cs*8, kd + slot*1024); \
    } \
    char* vd = lds + (buf)*40960 + 16384; \
    _Pragma("unroll") \
    for (int s=0;s<6;s++){ \
      int slot = w*6+s; int dvr = slot*8 + vl_row; int cs = vl_c ^ (dvr&7); \
      g2l16(Vb + (size_t)dvr*SEQ + (size_t)(jt_)*64 + cs*8, vd + slot*1024); \
    } } while(0)

  int jt0 = half*16;
  STAGE(0, jt0);

  const float CS = SCALEQK * (2.f*LOG2E/5.f);
  const float CB = 2.f*LOG2E/5.f;
  const float CP = 5.f*LOG2E;

  for (int jj=0; jj<16; jj++){
    int jt = jt0 + jj;
    int cur = jj & 1;
    __syncthreads();
    if (jj < 15) STAGE(cur^1, jt+1);
    const char* kb_ = lds + cur*40960;
    const char* vb_ = lds + cur*40960 + 16384;

    f32x16 s0 = zero16(), s1 = zero16();
    __builtin_amdgcn_s_setprio(1);
    #pragma unroll
    for (int ks=0; ks<8; ks++){
      int cso = ((2*ks + h) ^ (li&7))*16;
      f16x8 kf0 = *(const f16x8*)(kb_ + (     li)*256 + cso);
      f16x8 kf1 = *(const f16x8*)(kb_ + (32 + li)*256 + cso);
      s0 = MFMA32(kf0, qf[ks], s0);
      s1 = MFMA32(kf1, qf[ks], s1);
    }
    __builtin_amdgcn_s_setprio(0);

    f16x8 pa[2][2];
    #pragma unroll
    for (int sub=0; sub<2; sub++){
      const f32x16& sacc = sub ? s1 : s0;
      int jb4 = jt*16 + sub*8;
      f16x8 bv = *(const f16x8*)(brow + jb4);
      float bt[4];
      #pragma unroll
      for (int q=0;q<4;q++){
        float b0 = (float)bv[2*q], b1 = (float)bv[2*q+1];
        bt[q] = (h ? b1 : b0) * CB;
      }
      float p[16], xp[16];
      #pragma unroll
      for (int r=0;r<16;r++){
        float u2 = sacc[r]*CS + bt[r>>2];
        float E  = fexp2(u2);
        float tn = 1.f - 2.f*frcp(E + 1.f);
        float pr = fexp2(tn * CP);
        p[r] = pr;
        lsum += pr;
      }
      #pragma unroll
      for (int r=0;r<16;r++) xp[r] = __shfl_xor(p[r], 32);
      #pragma unroll
      for (int ks2=0; ks2<2; ks2++){
        #pragma unroll
        for (int e=0;e<4;e++) pa[sub][ks2][e] = (f16)(h ? xp[8*ks2+4+e] : p[8*ks2+e]);
        #pragma unroll
        for (int e=4;e<8;e++) pa[sub][ks2][e] = (f16)(h ? p[8*ks2+e]    : xp[8*ks2+e-4]);
      }
    }
    __builtin_amdgcn_s_setprio(1);
    #pragma unroll
    for (int sub=0; sub<2; sub++)
      #pragma unroll
      for (int ks2=0; ks2<2; ks2++)
        #pragma unroll
        for (int nf=0; nf<6; nf++){
          int dvr = nf*32 + li;
          int cj = (sub*4 + 2*ks2 + h) ^ (dvr&7);
          f16x8 vf = *(const f16x8*)(vb_ + dvr*128 + cj*16);
          oacc[nf] = MFMA32(pa[sub][ks2], vf, oacc[nf]);
        }
    __builtin_amdgcn_s_setprio(0);
  }
  f16* Ob = Opart + (size_t)(bgqt*2 + half)*128*192;
  #pragma unroll
  for (int nf=0; nf<6; nf++)
    #pragma unroll
    for (int r=0;r<16;r++){
      int il = (r&3) + 8*(r>>2) + 4*h;
      Ob[(size_t)(w*32 + il)*192 + nf*32 + li] = (f16)oacc[nf][r];
    }
  float ltot = lsum + __shfl_xor(lsum, 32);
  if (h == 0) Ls[(size_t)(bgqt*2 + half)*128 + w*32 + li] = ltot;
#undef STAGE
}

// ================= K5b: combine f16 partials -> AO (f16) =================
__global__ __launch_bounds__(256) void attn_combine(const f16* __restrict__ Opart,
                                                    const float* __restrict__ Ls,
                                                    f16* __restrict__ AO){
  int tid = threadIdx.x;
  int pr = blockIdx.x*16 + (tid>>4);
  int sub = tid & 15;
  int bgqt = pr >> 7, row = pr & 127;
  int bg = bgqt & 15, qt = bgqt >> 4;
  int b = bg >> 3, g = bg & 7;
  int n = qt*128 + row;
  float l0 = Ls[(size_t)(bgqt*2 + 0)*128 + row];
  float l1 = Ls[(size_t)(bgqt*2 + 1)*128 + row];
  float linv = 1.f / (l0 + l1);
  const f16* O0 = Opart + ((size_t)(bgqt*2 + 0)*128 + row)*192 + sub*12;
  const f16* O1 = Opart + ((size_t)(bgqt*2 + 1)*128 + row)*192 + sub*12;
  f16* dst = AO + ((size_t)(b*SEQ + n)*NHEADS + g)*DVV + sub*12;
  #pragma unroll
  for (int j=0;j<3;j++){
    f16x4 a = *(const f16x4*)(O0 + 4*j);
    f16x4 c = *(const f16x4*)(O1 + 4*j);
    f16x4 o;
    #pragma unroll
    for (int e=0;e<4;e++) o[e] = (f16)(((float)a[e] + (float)c[e]) * linv);
    *(f16x4*)(dst + 4*j) = o;
  }
}

// ================= K6: out GEMM (256x64 tile, XCD-chunked) =================
DEV void gemm256_body(const f16* __restrict__ A, const f16* __restrict__ WT,
                      float* __restrict__ C, int ldc, const float* __restrict__ bo,
                      char* lds, int bx, int by, int tid){
  int nb = bx*64, mb = by*256;
  int w = tid>>6, lane = tid&63, li = lane&31, h = lane>>5;
  int srow = lane>>3, sc = lane&7;
  f32x16 acc[2][2];
  acc[0][0]=zero16(); acc[0][1]=zero16(); acc[1][0]=zero16(); acc[1][1]=zero16();

#define G_STAGE(buf, kt_) do { \
    char* ad = lds + (buf)*40960; \
    _Pragma("unroll") \
    for (int s=0;s<8;s++){ \
      int slot = w*8+s; int mlr = slot*8 + srow; int cs = sc ^ (srow&7); \
      g2l16(A + (size_t)(mb+mlr)*DMODEL + (kt_)*64 + cs*8, ad + slot*1024); \
    } \
    char* bd = lds + (buf)*40960 + 32768; \
    _Pragma("unroll") \
    for (int s=0;s<2;s++){ \
      int slot = w*2+s; int nl = slot*8 + srow; int cs = sc ^ (srow&7); \
      g2l16(WT + (size_t)(nb+nl)*DMODEL + (kt_)*64 + cs*8, bd + slot*1024); \
    } } while(0)

  G_STAGE(0,0);
  __syncthreads();
  for (int kt=0; kt<24; kt++){
    int cur = kt&1;
    if (kt<23) G_STAGE(cur^1, kt+1);
    const char* ad = lds + cur*40960;
    const char* bd = lds + cur*40960 + 32768;
    #pragma unroll
    for (int ks=0; ks<4; ks++){
      int cso = ((2*ks+h) ^ (li&7))*16;
      f16x8 a0 = *(const f16x8*)(ad + (w*64      + li)*128 + cso);
      f16x8 a1 = *(const f16x8*)(ad + (w*64 + 32 + li)*128 + cso);
      f16x8 b0 = *(const f16x8*)(bd + (           li)*128 + cso);
      f16x8 b1 = *(const f16x8*)(bd + (      32 + li)*128 + cso);
      acc[0][0] = MFMA32(a0, b0, acc[0][0]);
      acc[0][1] = MFMA32(a0, b1, acc[0][1]);
      acc[1][0] = MFMA32(a1, b0, acc[1][0]);
      acc[1][1] = MFMA32(a1, b1, acc[1][1]);
    }
    __syncthreads();
  }
  float bo0 = bo ? bo[nb+li] : 0.f, bo1 = bo ? bo[nb+32+li] : 0.f;
  #pragma unroll
  for (int mi=0; mi<2; mi++)
    #pragma unroll
    for (int nf=0; nf<2; nf++)
      #pragma unroll
      for (int r=0;r<16;r++){
        int m = mb + w*64 + mi*32 + (r&3) + 8*(r>>2) + 4*h;
        int n = nb + nf*32 + li;
        C[(size_t)m*ldc + n] = acc[mi][nf][r] + (nf ? bo1 : bo0);
      }
#undef G_STAGE
}

__global__ __launch_bounds__(256,2) void out_gemm(const f16* __restrict__ A, const f16* __restrict__ WT,
                                                  const float* __restrict__ bo, float* __restrict__ out){
  __shared__ char lds[81920];
  int bid = blockIdx.x, tid = threadIdx.x;
  int l = (bid&7)*48 + (bid>>3);
  gemm256_body(A, WT, out, DMODEL, bo, lds, l%24, l/24, tid);
}

extern "C" void kernel_launch(void* const* d_in, const int* in_sizes, int n_in,
                              void* d_out, int out_size, void* d_ws, size_t ws_size,
                              hipStream_t stream) {
  (void)in_sizes; (void)n_in; (void)out_size; (void)ws_size;
  const float* x        = (const float*)d_in[0];
  const float* pairwise = (const float*)d_in[1];
  const float* w_qkv    = (const float*)d_in[2];
  const float* q_w      = (const float*)d_in[3];
  const float* q_b      = (const float*)d_in[4];
  const float* k_w      = (const float*)d_in[5];
  const float* k_b      = (const float*)d_in[6];
  const float* v_w      = (const float*)d_in[7];
  const float* v_b      = (const float*)d_in[8];
  const float* bgamma   = (const float*)d_in[9];
  const float* bbeta    = (const float*)d_in[10];
  const float* brvar    = (const float*)d_in[11];
  const float* w_bias   = (const float*)d_in[12];
  const float* w_out    = (const float*)d_in[13];
  const float* b_out    = (const float*)d_in[14];
  float* out = (float*)d_out;

  char* ws = (char*)d_ws;
  f16*   wqkvT = (f16*)(ws + OFF_WQKVT);
  f16*   woutT = (f16*)(ws + OFF_WOUTT);
  f16*   Xh    = (f16*)(ws + OFF_XH);
  f16*   Qh    = (f16*)(ws + OFF_Q);
  f16*   Kh    = (f16*)(ws + OFF_K);
  f16*   Vh    = (f16*)(ws + OFF_V);
  f16*   VTh   = (f16*)(ws + OFF_VT);
  float* part  = (float*)(ws + OFF_PART);
  float* sg    = (float*)(ws + OFF_SG);
  float* sb    = sg + 128;
  f16*   biasc = (f16*)(ws + OFF_BIASC);
  f16*   AOh   = (f16*)(ws + OFF_AO);
  f16*   Opart = (f16*)(ws + OFF_OP);
  float* Lsw   = (float*)(ws + OFF_LS);

  k1_prep<<<8416, 256, 0, stream>>>(w_qkv, wqkvT, w_out, woutT, x, Xh, pairwise, part);
  finvar_k<<<1, 256, 0, stream>>>(part, brvar, bgamma, bbeta, sg, sb);
  k2_qkvln_bias<<<1344, 256, 0, stream>>>(Xh, wqkvT, q_w,q_b,k_w,k_b,v_w,v_b,
                                          Qh, Kh, Vh, pairwise, sg, sb, w_bias, biasc);
  k4_vtrans<<<768, 256, 0, stream>>>(Vh, VTh);
  attn<<<512, 256, 0, stream>>>(Qh, Kh, VTh, biasc, Opart, Lsw);
  attn_combine<<<2048, 256, 0, stream>>>(Opart, Lsw, AOh);
  out_gemm<<<384, 256, 0, stream>>>(AOh, woutT, b_out, out);
}